// Round 8
// baseline (4859.115 us; speedup 1.0000x reference)
//
#include <hip/hip_runtime.h>
#include <hip/hip_bf16.h>

#define T_STEPS 2048
#define HDIM 256
#define VOUT 32000

typedef short short8 __attribute__((ext_vector_type(8)));
typedef float f32x4 __attribute__((ext_vector_type(4)));
typedef int i32x4 __attribute__((ext_vector_type(4)));

#if defined(__has_builtin)
#if __has_builtin(__builtin_amdgcn_rcpf)
#define HAVE_RCP 1
#endif
#endif

__device__ __forceinline__ float fast_rcp(float x) {
#ifdef HAVE_RCP
    return __builtin_amdgcn_rcpf(x);
#else
    return 1.0f / x;
#endif
}
__device__ __forceinline__ float fast_sigmoid(float x) {
    return fast_rcp(1.0f + __expf(-x));
}
__device__ __forceinline__ float fast_tanh(float x) {
    float ax = fabsf(x);
    float e = __expf(-2.0f * ax);
    float t = 1.0f - 2.0f * e * fast_rcp(1.0f + e);
    return copysignf(t, x);
}

// raw barrier: order LDS only; global loads/stores float across (no vmcnt drain)
__device__ __forceinline__ void barrier_lds() {
    asm volatile("s_waitcnt lgkmcnt(0)\n\ts_barrier" ::: "memory");
}

// ---------- quantize a 768x256 fp32 matrix to int8 (per-row scale) ----------
__global__ void k_quant(const float* __restrict__ W, int* __restrict__ wq,
                        float* __restrict__ sc) {
    int row = blockIdx.x;
    int t = threadIdx.x;
    float4 w = ((const float4*)(W + (size_t)row * HDIM))[t];
    float m = fmaxf(fmaxf(fabsf(w.x), fabsf(w.y)), fmaxf(fabsf(w.z), fabsf(w.w)));
#pragma unroll
    for (int off = 32; off; off >>= 1) m = fmaxf(m, __shfl_xor(m, off));
    float inv = (m > 0.0f) ? 127.0f / m : 0.0f;
    float scale = (m > 0.0f) ? m * (1.0f / 127.0f) : 0.0f;
    int q0 = __float2int_rn(w.x * inv); q0 = max(-127, min(127, q0));
    int q1 = __float2int_rn(w.y * inv); q1 = max(-127, min(127, q1));
    int q2 = __float2int_rn(w.z * inv); q2 = max(-127, min(127, q2));
    int q3 = __float2int_rn(w.w * inv); q3 = max(-127, min(127, q3));
    int packed = (q0 & 255) | ((q1 & 255) << 8) | ((q2 & 255) << 16) | ((q3 & 255) << 24);
    wq[row * 64 + t] = packed;
    if (t == 0) sc[row] = scale;
}

// ---------- fp32 -> bf16 (RNE, manual to keep ushort storage) ----------
__global__ __launch_bounds__(256) void k_cvt(const float* __restrict__ in,
                                             unsigned short* __restrict__ out, int n4) {
    int i = blockIdx.x * 256 + threadIdx.x;
    if (i < n4) {
        float4 v = ((const float4*)in)[i];
        unsigned int u[4] = {__float_as_uint(v.x), __float_as_uint(v.y),
                             __float_as_uint(v.z), __float_as_uint(v.w)};
        ushort4 o;
        o.x = (unsigned short)((u[0] + 0x7FFFu + ((u[0] >> 16) & 1)) >> 16);
        o.y = (unsigned short)((u[1] + 0x7FFFu + ((u[1] >> 16) & 1)) >> 16);
        o.z = (unsigned short)((u[2] + 0x7FFFu + ((u[2] >> 16) & 1)) >> 16);
        o.w = (unsigned short)((u[3] + 0x7FFFu + ((u[3] >> 16) & 1)) >> 16);
        ((ushort4*)out)[i] = o;
    }
}

// ---------- Phase A: gi[t][row] = W_ih @ x_t + b_ih (+ b_hh for r/z rows) ----------
__global__ __launch_bounds__(256) void k_gi(const int* __restrict__ toks,
                                            const float* __restrict__ emb,
                                            const float* __restrict__ W,
                                            const float* __restrict__ b,
                                            const float* __restrict__ bhh,
                                            float* __restrict__ gi, int do_relu) {
    __shared__ float4 xs[64];
    int t = blockIdx.x;
    int tid = threadIdx.x;
    int tok = toks[t];
    if (tid < 64) {
        float4 x = ((const float4*)(emb + (size_t)tok * HDIM))[tid];
        if (do_relu) {
            x.x = fmaxf(x.x, 0.0f); x.y = fmaxf(x.y, 0.0f);
            x.z = fmaxf(x.z, 0.0f); x.w = fmaxf(x.w, 0.0f);
        }
        xs[tid] = x;
    }
    __syncthreads();
#pragma unroll
    for (int g = 0; g < 3; ++g) {
        int row = tid + g * 256;
        const float4* wr = (const float4*)(W + (size_t)row * HDIM);
        float acc = b[row] + ((g < 2) ? bhh[row] : 0.0f);
#pragma unroll 16
        for (int k = 0; k < 64; ++k) {
            float4 w = wr[k];
            float4 x = xs[k];
            acc += w.x * x.x + w.y * x.y + w.z * x.z + w.w * x.w;
        }
        gi[(size_t)t * 768 + row] = acc;
    }
}

// ---------- Phase B: sequential double-GRU via TRANSPOSED i8 MFMA ----------
// D = mfma(A = h broadcast, B = W fragment): C-layout col=lane&15 means each
// lane ends holding the gate sum for ITS OWN element e = 32*wave + (lane&15)
// (row-redundant).  No GLDS bounce, no barrier-A: {mfma -> in-lane epilogue ->
// HQ byte write -> one lgkm barrier} per half-step.
// Fragment loads are byte-identical to the R5-validated ones (operands merely
// swap roles): B-frag of W == R5's A-frag (row=l&15, dwords (l>>4)*4+i per
// K-tile); A-frag of h == R5's B-frag (broadcast dwords (l>>4)*4+i).
// Wave w owns elements [32w,32w+32): 2 e-tiles x 3 gates = 6 tiles x 4 K = 24
// MFMAs; epilogue for 2 elements per lane; lanes with (l>>4)==0 write HQ.
// Integer sums exact -> h trajectory bit-identical to all prior rounds.
__global__ __launch_bounds__(512, 2) void k_gru(
    const int* __restrict__ wq_e, const float* __restrict__ sc_e,
    const float* __restrict__ bhh_e, const float* __restrict__ gi_e,
    const int* __restrict__ wq_d, const float* __restrict__ sc_d,
    const float* __restrict__ bhh_d, const float* __restrict__ gi_d,
    unsigned short* __restrict__ h_bf) {
    __shared__ __align__(16) int HQA[64];  // h input to encoder half
    __shared__ __align__(16) int HQB[64];  // h input to decoder half

    const int tid = threadIdx.x;
    const int w  = tid >> 6;   // wave 0..7 -> elements [32w, 32w+32)
    const int l  = tid & 63;
    const int lr = l & 15;     // element-in-tile / W-row-in-tile
    const int lk = l >> 4;     // k-group
    const int e1 = 32 * w + lr;
    const int e2 = e1 + 16;
    const bool duty = (lk == 0);

    // B-operand fragments (weights): tj = tau*3 + g; rows 256g + 32w + 16tau + lr
    i32x4 WE[6][4], WD[6][4];
#pragma unroll
    for (int tau = 0; tau < 2; ++tau)
#pragma unroll
        for (int g = 0; g < 3; ++g) {
            const int tj = tau * 3 + g;
            const int row = 256 * g + 32 * w + 16 * tau + lr;
#pragma unroll
            for (int kt = 0; kt < 4; ++kt) {
                WE[tj][kt] = *(const i32x4*)(wq_e + row * 64 + kt * 16 + lk * 4);
                WD[tj][kt] = *(const i32x4*)(wq_d + row * 64 + kt * 16 + lk * 4);
            }
        }

    const float se10 = sc_e[e1] * (1.0f / 127.0f);
    const float se11 = sc_e[e1 + 256] * (1.0f / 127.0f);
    const float se12 = sc_e[e1 + 512] * (1.0f / 127.0f);
    const float se20 = sc_e[e2] * (1.0f / 127.0f);
    const float se21 = sc_e[e2 + 256] * (1.0f / 127.0f);
    const float se22 = sc_e[e2 + 512] * (1.0f / 127.0f);
    const float sd10 = sc_d[e1] * (1.0f / 127.0f);
    const float sd11 = sc_d[e1 + 256] * (1.0f / 127.0f);
    const float sd12 = sc_d[e1 + 512] * (1.0f / 127.0f);
    const float sd20 = sc_d[e2] * (1.0f / 127.0f);
    const float sd21 = sc_d[e2 + 256] * (1.0f / 127.0f);
    const float sd22 = sc_d[e2 + 512] * (1.0f / 127.0f);
    const float be1 = bhh_e[e1 + 512], be2 = bhh_e[e2 + 512];
    const float bd1 = bhh_d[e1 + 512], bd2 = bhh_d[e2 + 512];

    float h1 = 0.0f, h2 = 0.0f;
    if (tid < 64) HQA[tid] = 0;
    __syncthreads();

    const float* ge = gi_e;
    const float* gd = gi_d;
    unsigned short* hop = h_bf;
    const i32x4 z4 = {0, 0, 0, 0};

    // one half-step; returns via h1/h2 update
    auto half = [&](const i32x4(&W)[6][4],
                    float g10, float g11, float g12, float g20, float g21, float g22,
                    float s10, float s11, float s12, float s20, float s21, float s22,
                    float bn1, float bn2, const int* HQr, int* HQw,
                    unsigned short* hout) {
        // A-operand: h broadcast (col-of-C independent of row)
        i32x4 A0 = *(const i32x4*)(HQr + 0 * 16 + lk * 4);
        i32x4 A1 = *(const i32x4*)(HQr + 1 * 16 + lk * 4);
        i32x4 A2 = *(const i32x4*)(HQr + 2 * 16 + lk * 4);
        i32x4 A3 = *(const i32x4*)(HQr + 3 * 16 + lk * 4);
        i32x4 acc0, acc1, acc2, acc3, acc4, acc5;
        {
            i32x4 a;
            a = __builtin_amdgcn_mfma_i32_16x16x64_i8(A0, W[0][0], z4, 0, 0, 0);
            a = __builtin_amdgcn_mfma_i32_16x16x64_i8(A1, W[0][1], a, 0, 0, 0);
            a = __builtin_amdgcn_mfma_i32_16x16x64_i8(A2, W[0][2], a, 0, 0, 0);
            acc0 = __builtin_amdgcn_mfma_i32_16x16x64_i8(A3, W[0][3], a, 0, 0, 0);
            a = __builtin_amdgcn_mfma_i32_16x16x64_i8(A0, W[1][0], z4, 0, 0, 0);
            a = __builtin_amdgcn_mfma_i32_16x16x64_i8(A1, W[1][1], a, 0, 0, 0);
            a = __builtin_amdgcn_mfma_i32_16x16x64_i8(A2, W[1][2], a, 0, 0, 0);
            acc1 = __builtin_amdgcn_mfma_i32_16x16x64_i8(A3, W[1][3], a, 0, 0, 0);
            a = __builtin_amdgcn_mfma_i32_16x16x64_i8(A0, W[2][0], z4, 0, 0, 0);
            a = __builtin_amdgcn_mfma_i32_16x16x64_i8(A1, W[2][1], a, 0, 0, 0);
            a = __builtin_amdgcn_mfma_i32_16x16x64_i8(A2, W[2][2], a, 0, 0, 0);
            acc2 = __builtin_amdgcn_mfma_i32_16x16x64_i8(A3, W[2][3], a, 0, 0, 0);
            a = __builtin_amdgcn_mfma_i32_16x16x64_i8(A0, W[3][0], z4, 0, 0, 0);
            a = __builtin_amdgcn_mfma_i32_16x16x64_i8(A1, W[3][1], a, 0, 0, 0);
            a = __builtin_amdgcn_mfma_i32_16x16x64_i8(A2, W[3][2], a, 0, 0, 0);
            acc3 = __builtin_amdgcn_mfma_i32_16x16x64_i8(A3, W[3][3], a, 0, 0, 0);
            a = __builtin_amdgcn_mfma_i32_16x16x64_i8(A0, W[4][0], z4, 0, 0, 0);
            a = __builtin_amdgcn_mfma_i32_16x16x64_i8(A1, W[4][1], a, 0, 0, 0);
            a = __builtin_amdgcn_mfma_i32_16x16x64_i8(A2, W[4][2], a, 0, 0, 0);
            acc4 = __builtin_amdgcn_mfma_i32_16x16x64_i8(A3, W[4][3], a, 0, 0, 0);
            a = __builtin_amdgcn_mfma_i32_16x16x64_i8(A0, W[5][0], z4, 0, 0, 0);
            a = __builtin_amdgcn_mfma_i32_16x16x64_i8(A1, W[5][1], a, 0, 0, 0);
            a = __builtin_amdgcn_mfma_i32_16x16x64_i8(A2, W[5][2], a, 0, 0, 0);
            acc5 = __builtin_amdgcn_mfma_i32_16x16x64_i8(A3, W[5][3], a, 0, 0, 0);
        }
        // element e1 (tiles tau=0: acc0..2)
        {
            float f0 = (float)acc0[0], f1 = (float)acc1[0], f2 = (float)acc2[0];
            float r = fast_sigmoid(g10 + s10 * f0);
            float z = fast_sigmoid(g11 + s11 * f1);
            float n = fast_tanh(g12 + r * (s12 * f2 + bn1));
            h1 = (1.0f - z) * n + z * h1;
        }
        // element e2 (tiles tau=1: acc3..5)
        {
            float f0 = (float)acc3[0], f1 = (float)acc4[0], f2 = (float)acc5[0];
            float r = fast_sigmoid(g20 + s20 * f0);
            float z = fast_sigmoid(g21 + s21 * f1);
            float n = fast_tanh(g22 + r * (s22 * f2 + bn2));
            h2 = (1.0f - z) * n + z * h2;
        }
        if (duty) {
            ((signed char*)HQw)[e1] = (signed char)__float2int_rn(h1 * 127.0f);
            ((signed char*)HQw)[e2] = (signed char)__float2int_rn(h2 * 127.0f);
            if (hout) {
                unsigned int u1 = __float_as_uint(h1);
                unsigned int u2 = __float_as_uint(h2);
                hout[e1] = (unsigned short)((u1 + 0x7FFFu + ((u1 >> 16) & 1)) >> 16);
                hout[e2] = (unsigned short)((u2 + 0x7FFFu + ((u2 >> 16) & 1)) >> 16);
            }
        }
        barrier_lds();
    };

    // prologue prefetch: encoder gi of step 0
    float eA0 = ge[e1], eA1 = ge[e1 + 256], eA2 = ge[e1 + 512];
    float eB0 = ge[e2], eB1 = ge[e2 + 256], eB2 = ge[e2 + 512];

    for (int t = 0; t < T_STEPS; ++t) {
        // prefetch decoder gi of THIS step (consumed ~a half-step from now)
        float dA0 = gd[e1], dA1 = gd[e1 + 256], dA2 = gd[e1 + 512];
        float dB0 = gd[e2], dB1 = gd[e2 + 256], dB2 = gd[e2 + 512];
        gd += 768;

        // ---- encoder half: HQA -> HQB ----
        half(WE, eA0, eA1, eA2, eB0, eB1, eB2,
             se10, se11, se12, se20, se21, se22, be1, be2, HQA, HQB, nullptr);

        // prefetch encoder gi of NEXT step (consumed a full step from now).
        // Last iteration: clamp back inside gi_e (values unused).
        {
            const float* gen = (t < T_STEPS - 1) ? (ge + 768) : gi_e;
            eA0 = gen[e1]; eA1 = gen[e1 + 256]; eA2 = gen[e1 + 512];
            eB0 = gen[e2]; eB1 = gen[e2 + 256]; eB2 = gen[e2 + 512];
            ge = gen;
        }

        // ---- decoder half: HQB -> HQA ----
        half(WD, dA0, dA1, dA2, dB0, dB1, dB2,
             sd10, sd11, sd12, sd20, sd21, sd22, bd1, bd2, HQB, HQA, hop);
        hop += 256;
    }
}

// ---------- Phase C1: logits = H(2048x256) @ out_W^T + b via bf16 MFMA ----------
__global__ __launch_bounds__(256) void k_logits(const unsigned short* __restrict__ hb,
                                                const unsigned short* __restrict__ wb,
                                                const float* __restrict__ out_b,
                                                float* __restrict__ out) {
    const int vb = blockIdx.x * 64;
    const int tb = blockIdx.y * 64;
    const int w = threadIdx.x >> 6;
    const int l = threadIdx.x & 63;
    const int m = l & 15;
    const int q = l >> 4;

    const unsigned short* aptr = hb + (size_t)(tb + w * 16 + m) * HDIM + q * 8;
    const unsigned short* bptr = wb + (size_t)(vb + m) * HDIM + q * 8;

    short8 af[8];
#pragma unroll
    for (int kt = 0; kt < 8; ++kt) af[kt] = *(const short8*)(aptr + kt * 32);

    f32x4 acc[4];
#pragma unroll
    for (int nt = 0; nt < 4; ++nt)
#pragma unroll
        for (int r = 0; r < 4; ++r) acc[nt][r] = 0.0f;

#pragma unroll
    for (int nt = 0; nt < 4; ++nt) {
        const unsigned short* bp = bptr + (size_t)nt * 16 * HDIM;
#pragma unroll
        for (int kt = 0; kt < 8; ++kt) {
            short8 bf = *(const short8*)(bp + kt * 32);
            acc[nt] = __builtin_amdgcn_mfma_f32_16x16x32_bf16(af[kt], bf, acc[nt], 0, 0, 0);
        }
    }
#pragma unroll
    for (int nt = 0; nt < 4; ++nt) {
        float bias = out_b[vb + nt * 16 + m];
#pragma unroll
        for (int r = 0; r < 4; ++r) {
            out[(size_t)(tb + w * 16 + q * 4 + r) * VOUT + vb + nt * 16 + m] =
                acc[nt][r] + bias;
        }
    }
}

// ---------- Phase C2+C3 fused: per-row logsumexp then subtract ----------
__global__ __launch_bounds__(256) void k_lsesub(float* __restrict__ out) {
    const int t = blockIdx.x;
    const int tid = threadIdx.x;
    float* rowp = out + (size_t)t * VOUT;
    float m = -3.0e38f, l = 0.0f;
    for (int v = tid; v < VOUT; v += 256) {
        float x = rowp[v];
        float M = fmaxf(m, x);
        l = l * __expf(m - M) + __expf(x - M);
        m = M;
    }
#pragma unroll
    for (int off = 32; off; off >>= 1) {
        float m2 = __shfl_xor(m, off);
        float l2 = __shfl_xor(l, off);
        float M = fmaxf(m, m2);
        l = l * __expf(m - M) + l2 * __expf(m2 - M);
        m = M;
    }
    __shared__ float sm[4], sl[4];
    __shared__ float s_lse;
    int lane = tid & 63, wv = tid >> 6;
    if (lane == 0) { sm[wv] = m; sl[wv] = l; }
    __syncthreads();
    if (tid == 0) {
        float M = fmaxf(fmaxf(sm[0], sm[1]), fmaxf(sm[2], sm[3]));
        float L = sl[0] * __expf(sm[0] - M) + sl[1] * __expf(sm[1] - M) +
                  sl[2] * __expf(sm[2] - M) + sl[3] * __expf(sm[3] - M);
        s_lse = M + __logf(L);
    }
    __syncthreads();
    float s = s_lse;
    float4* p4 = (float4*)rowp;
    for (int i = tid; i < VOUT / 4; i += 256) {
        float4 o = p4[i];
        o.x -= s; o.y -= s; o.z -= s; o.w -= s;
        p4[i] = o;
    }
}

extern "C" void kernel_launch(void* const* d_in, const int* in_sizes, int n_in,
                              void* d_out, int out_size, void* d_ws, size_t ws_size,
                              hipStream_t stream) {
    (void)in_sizes; (void)n_in; (void)out_size; (void)ws_size;
    const int*   src      = (const int*)d_in[0];
    const int*   trg      = (const int*)d_in[1];
    const float* enc_emb  = (const float*)d_in[2];
    const float* enc_W_ih = (const float*)d_in[3];
    const float* enc_W_hh = (const float*)d_in[4];
    const float* enc_b_ih = (const float*)d_in[5];
    const float* enc_b_hh = (const float*)d_in[6];
    const float* dec_emb  = (const float*)d_in[7];
    const float* dec_W_ih = (const float*)d_in[8];
    const float* dec_W_hh = (const float*)d_in[9];
    const float* dec_b_ih = (const float*)d_in[10];
    const float* dec_b_hh = (const float*)d_in[11];
    const float* out_W    = (const float*)d_in[12];
    const float* out_b    = (const float*)d_in[13];
    float* out = (float*)d_out;

    char* ws = (char*)d_ws;
    float* gi_e  = (float*)ws; ws += (size_t)T_STEPS * 768 * 4;
    float* gi_d  = (float*)ws; ws += (size_t)T_STEPS * 768 * 4;
    float* sc_e  = (float*)ws; ws += 768 * 4;
    float* sc_d  = (float*)ws; ws += 768 * 4;
    int*   wq_e  = (int*)ws;   ws += 768 * 64 * 4;
    int*   wq_d  = (int*)ws;   ws += 768 * 64 * 4;
    unsigned short* h_bf = (unsigned short*)ws; ws += (size_t)T_STEPS * HDIM * 2;
    unsigned short* w_bf = (unsigned short*)ws; ws += (size_t)VOUT * HDIM * 2;

    k_quant<<<768, 64, 0, stream>>>(enc_W_hh, wq_e, sc_e);
    k_quant<<<768, 64, 0, stream>>>(dec_W_hh, wq_d, sc_d);
    k_cvt<<<(VOUT * HDIM / 4 + 255) / 256, 256, 0, stream>>>(out_W, w_bf, VOUT * HDIM / 4);
    k_gi<<<T_STEPS, 256, 0, stream>>>(src, enc_emb, enc_W_ih, enc_b_ih, enc_b_hh, gi_e, 0);
    k_gi<<<T_STEPS, 256, 0, stream>>>(trg, dec_emb, dec_W_ih, dec_b_ih, dec_b_hh, gi_d, 1);
    k_gru<<<1, 512, 0, stream>>>(wq_e, sc_e, enc_b_hh, gi_e,
                                 wq_d, sc_d, dec_b_hh, gi_d, h_bf);
    k_logits<<<dim3(VOUT / 64, T_STEPS / 64), 256, 0, stream>>>(h_bf, w_bf, out_b, out);
    k_lsesub<<<T_STEPS, 256, 0, stream>>>(out);
}